// Round 11
// baseline (848.240 us; speedup 1.0000x reference)
//
#include <hip/hip_runtime.h>
#include <math.h>

#define VSZ 50000
#define HD 600
#define HHD 300
#define LATD 100
#define MLEN 50
#define TIN 48
#define TTGT 50
#define NBLK 75
#define NTHR 512
#define NTOT (NBLK*NTHR)
#define ESTR 640              // padded row stride
#define SLOT_STRIDE 32        // ints; 128B between slots
#define SENTU 0x40000000u     // 2.0f — impossible GRU output (|h| < 1 strictly)

typedef __attribute__((ext_vector_type(4))) float f32x4;
typedef __attribute__((ext_vector_type(8))) short s16x8;

__device__ __forceinline__ float sigf(float x){ return 1.0f/(1.0f+__expf(-x)); }

// agent-scope store (write-through to coherent point)
__device__ __forceinline__ void stf(float* p, float v){
    __hip_atomic_store((unsigned int*)p, __float_as_uint(v),
                       __ATOMIC_RELAXED, __HIP_MEMORY_SCOPE_AGENT);
}
__device__ __forceinline__ void stu(float* p, unsigned v){
    __hip_atomic_store((unsigned int*)p, v,
                       __ATOMIC_RELAXED, __HIP_MEMORY_SCOPE_AGENT);
}
__device__ __forceinline__ int ldslot(const int* p){
    return __hip_atomic_load(p, __ATOMIC_RELAXED, __HIP_MEMORY_SCOPE_AGENT);
}
__device__ __forceinline__ void stslot(int* p, int v){
    __hip_atomic_store(p, v, __ATOMIC_RELAXED, __HIP_MEMORY_SCOPE_AGENT);
}

// uncached 16B load (bypasses L1+L2 -> coherent point), waits completion
__device__ __forceinline__ f32x4 ld_unc16(const float* p){
    f32x4 r;
    asm volatile("global_load_dwordx4 %0, %1, off sc0 sc1\n\ts_waitcnt vmcnt(0)"
                 : "=v"(r) : "v"(p) : "memory");
    return r;
}
// poll a 16B chunk until no word equals the sentinel
__device__ __forceinline__ f32x4 poll16(const float* p){
    f32x4 r = ld_unc16(p);
    while (__float_as_uint(r[0])==SENTU || __float_as_uint(r[1])==SENTU ||
           __float_as_uint(r[2])==SENTU || __float_as_uint(r[3])==SENTU){
        __builtin_amdgcn_s_sleep(1);
        r = ld_unc16(p);
    }
    return r;
}

__device__ __forceinline__ void redu3(float&a,float&b,float&c){
    #pragma unroll
    for(int off=32;off;off>>=1){
        a+=__shfl_xor(a,off); b+=__shfl_xor(b,off); c+=__shfl_xor(c,off);
    }
}
__device__ __forceinline__ void redu6(float&a,float&b,float&c,float&d,float&e,float&f){
    #pragma unroll
    for(int off=32;off;off>>=1){
        a+=__shfl_xor(a,off); b+=__shfl_xor(b,off); c+=__shfl_xor(c,off);
        d+=__shfl_xor(d,off); e+=__shfl_xor(e,off); f+=__shfl_xor(f,off);
    }
}

// Two-level leader barrier (4 uses: pre + latent x3)
__device__ __forceinline__ void gridbar(int* slots, int* flags, int e){
    asm volatile("s_waitcnt vmcnt(0)" ::: "memory");
    __syncthreads();
    const int tid = threadIdx.x;
    if (tid == 0) stslot(&slots[blockIdx.x*SLOT_STRIDE], e);
    if (blockIdx.x == 0){
        if (tid < NBLK){
            while (ldslot(&slots[tid*SLOT_STRIDE]) < e)
                __builtin_amdgcn_s_sleep(1);
        }
        __syncthreads();
        if (tid < NBLK) stslot(&flags[tid*SLOT_STRIDE], e);
    } else {
        if (tid == 0){
            while (ldslot(&flags[blockIdx.x*SLOT_STRIDE]) < e)
                __builtin_amdgcn_s_sleep(1);
        }
    }
    __syncthreads();
}

__global__ void k_init(int* sync_mem){
    int i = blockIdx.x*blockDim.x + threadIdx.x;
    if (i < 2*NBLK*SLOT_STRIDE) sync_mem[i] = 0;
}

__global__ void __launch_bounds__(NTHR, 2) k_seq(
    const float* __restrict__ emb_enc, const float* __restrict__ emb_dec,
    const float* __restrict__ enc_wih_f, const float* __restrict__ enc_whh_f,
    const float* __restrict__ enc_bih_f, const float* __restrict__ enc_bhh_f,
    const float* __restrict__ enc_wih_b, const float* __restrict__ enc_whh_b,
    const float* __restrict__ enc_bih_b, const float* __restrict__ enc_bhh_b,
    const float* __restrict__ dec_wih_f, const float* __restrict__ dec_whh_f,
    const float* __restrict__ dec_bih_f, const float* __restrict__ dec_bhh_f,
    const float* __restrict__ dec_wih_b, const float* __restrict__ dec_whh_b,
    const float* __restrict__ dec_bih_b, const float* __restrict__ dec_bhh_b,
    const float* __restrict__ w_mean, const float* __restrict__ b_mean,
    const float* __restrict__ w_logv, const float* __restrict__ b_logv,
    const float* __restrict__ w_l2h, const float* __restrict__ b_l2h,
    const float* __restrict__ attn_w, const float* __restrict__ attn_b,
    const float* __restrict__ comb_w, const float* __restrict__ comb_b,
    const float* __restrict__ eps, const int* __restrict__ in_toks,
    const int* __restrict__ tgt_toks,
    float* __restrict__ GIf, float* __restrict__ ENCf,
    float* __restrict__ Zf, float* __restrict__ LATf, float* __restrict__ Mf,
    float* __restrict__ APREf, float* __restrict__ CPREf,
    float* __restrict__ HSs, float* __restrict__ HSv,
    float* __restrict__ out_mean, float* __restrict__ out_logv,
    int* slots, int* flags){

    __shared__ float h_lds[ESTR];
    __shared__ float o_lds[ESTR];
    __shared__ float s_lds[64];
    __shared__ float aw_lds[64];
    __shared__ float big_lds[HD*MLEN];  // encoder: ENC[50][600]; decoder: Mf[600][50]

    const int tid  = threadIdx.x;
    const int lane = tid & 63;
    const int wid  = tid >> 6;
    const int gtid = blockIdx.x*NTHR + tid;
    const int gw   = blockIdx.x*8 + wid;      // 0..599, == dir*HHD + k
    const int dir  = gw / HHD;
    const int k    = gw % HHD;
    int ep = 0;

    // own-direction chunk range for encoder polling (mixed block 37 -> full row)
    const int dlo = (blockIdx.x*8) / HHD, dhi = (blockIdx.x*8 + 7) / HHD;
    const int clo = (dlo==dhi) ? dlo*75 : 0;
    const int chi = (dlo==dhi) ? clo+75 : 150;
    const int flo = 4*clo, fhi = 4*chi;

    // zero ALL of h_lds/o_lds (incl. other-direction half + pads) — masked-weight
    // FMAs read these as finite zeros
    for (int j=tid; j<ESTR; j+=NTHR){ h_lds[j]=0.f; o_lds[j]=0.f; }

    // ---------------- PRE PHASE ----------------
    for (int idx=gtid; idx<TIN*HD; idx+=NTOT){
        int t=idx/HD, j=idx%HD;
        stu(&ENCf[(long)t*ESTR + j], SENTU);
    }
    for (int idx=gtid; idx<TTGT*HD; idx+=NTOT){
        int t=idx/HD, j=idx%HD;
        stu(&HSs[(long)t*ESTR + j], SENTU);
    }
    // GI: R1-exact bias-seeded single fmaf chain
    for (int idx=gtid; idx<TIN*1800; idx+=NTOT){
        int t=idx/1800, r=idx%1800, d=r/900, j=r%900;
        const float* w  = d ? enc_wih_b : enc_wih_f;
        const float* bi = d ? enc_bih_b : enc_bih_f;
        const float* x  = emb_enc + (long)in_toks[t]*HD;
        const float* wr = w + (long)j*HD;
        float acc = bi[j];
        for (int kk=0;kk<HD;kk+=4){
            float4 wv = *(const float4*)(wr+kk);
            float4 xv = *(const float4*)(x+kk);
            acc = fmaf(wv.x,xv.x,acc); acc = fmaf(wv.y,xv.y,acc);
            acc = fmaf(wv.z,xv.z,acc); acc = fmaf(wv.w,xv.w,acc);
        }
        stf(&GIf[idx], acc);
    }
    for (int idx=gtid; idx<TTGT*MLEN; idx+=NTOT){
        int t=idx/MLEN, a=idx%MLEN;
        int tok = t ? tgt_toks[t-1] : 1;
        const float* x  = emb_dec + (long)tok*HD;
        const float* wr = attn_w + (long)a*1200;
        float acc = attn_b[a];
        for (int kk=0;kk<HD;kk+=4){
            float4 wv = *(const float4*)(wr+kk);
            float4 xv = *(const float4*)(x+kk);
            acc = fmaf(wv.x,xv.x,acc); acc = fmaf(wv.y,xv.y,acc);
            acc = fmaf(wv.z,xv.z,acc); acc = fmaf(wv.w,xv.w,acc);
        }
        stf(&APREf[idx], acc);
    }
    for (int idx=gtid; idx<TTGT*HD; idx+=NTOT){
        int t=idx/HD, j=idx%HD;
        int tok = t ? tgt_toks[t-1] : 1;
        const float* x  = emb_dec + (long)tok*HD;
        const float* wr = comb_w + (long)j*1200;
        float acc = comb_b[j];
        for (int kk=0;kk<HD;kk+=4){
            float4 wv = *(const float4*)(wr+kk);
            float4 xv = *(const float4*)(x+kk);
            acc = fmaf(wv.x,xv.x,acc); acc = fmaf(wv.y,xv.y,acc);
            acc = fmaf(wv.z,xv.z,acc); acc = fmaf(wv.w,xv.w,acc);
        }
        stf(&CPREf[idx], acc);
    }
    gridbar(slots, flags, ++ep);   // sentinels + GI/APRE/CPRE visible

    // ---------------- ENCODER (48 steps, per-direction data-poll) ----------
    {
        const float* whh = dir ? enc_whh_b : enc_whh_f;
        const float* bhh = dir ? enc_bhh_b : enc_bhh_f;
        float wr_[5], wz_[5], wn_[5];
        #pragma unroll
        for (int i=0;i<5;i++){
            int k2 = lane + 64*i;
            bool ok = k2 < HHD;
            wr_[i] = ok ? whh[(long)k*HHD + k2] : 0.f;
            wz_[i] = ok ? whh[(long)(HHD+k)*HHD + k2] : 0.f;
            wn_[i] = ok ? whh[(long)(2*HHD+k)*HHD + k2] : 0.f;
        }
        const float bhr = bhh[k], bhz = bhh[HHD+k], bhn = bhh[2*HHD+k];
        float gr=0, gz=0, gn=0;
        if (lane < TIN){
            const float* g = GIf + (long)lane*1800 + dir*900;   // cached, post-bar
            gr = g[k]; gz = g[HHD+k]; gn = g[2*HHD+k];
        }
        for (int t=0; t<TIN; t++){
            if (t){
                if (tid < chi-clo)
                    *(f32x4*)&h_lds[4*(clo+tid)] = poll16(&ENCf[(long)(t-1)*ESTR + 4*(clo+tid)]);
            }
            // t==0: h_lds already fully zero
            __syncthreads();
            if (t){   // archive own half of row t-1
                for (int j=flo+tid; j<fhi; j+=NTHR)
                    big_lds[(long)(t-1)*HD + j] = h_lds[j];
            }
            float sr=0, sz=0, sn=0;
            #pragma unroll
            for (int i=0;i<5;i++){
                float hv = h_lds[dir*HHD + lane + 64*i];
                sr = fmaf(wr_[i], hv, sr);
                sz = fmaf(wz_[i], hv, sz);
                sn = fmaf(wn_[i], hv, sn);
            }
            redu3(sr, sz, sn);
            float grt=__shfl(gr,t), gzt=__shfl(gz,t), gnt=__shfl(gn,t);
            if (lane==0){
                float r = sigf(grt + sr + bhr);
                float z = sigf(gzt + sz + bhz);
                float n = tanhf(gnt + r*(sn + bhn));
                float hp = h_lds[gw];
                // direct per-wave store — issues as soon as THIS wave finishes
                stf(&ENCf[(long)t*ESTR + gw], (1.f-z)*n + z*hp);
            }
            __syncthreads();   // protect h_lds before next step's poll overwrite
        }
        // epilogue: pull row 47 FULL (gates on both chains), archive, zeros 48/49
        if (tid < HD/4)
            *(f32x4*)&h_lds[4*tid] = poll16(&ENCf[(long)(TIN-1)*ESTR + 4*tid]);
        __syncthreads();
        big_lds[(long)(TIN-1)*HD + tid] = h_lds[tid];
        if (tid < HD-NTHR) big_lds[(long)(TIN-1)*HD + NTHR + tid] = h_lds[NTHR+tid];
        big_lds[(long)TIN*HD + tid] = 0.f;
        big_lds[(long)TIN*HD + NTHR + tid] = 0.f;
        if (tid < 2*HD - 2*NTHR) big_lds[(long)TIN*HD + 2*NTHR + tid] = 0.f;
        // bulk-fill other-direction halves of rows 0..46
        {
            int compn = 150 - (chi - clo);
            for (int q=tid; q<47*compn; q+=NTHR){
                int row = q / compn, c = q % compn;
                int ch = (c < clo) ? c : (c + (chi - clo));
                *(f32x4*)&big_lds[(long)row*HD + 4*ch] =
                    poll16(&ENCf[(long)row*ESTR + 4*ch]);
            }
        }
        __syncthreads();
    }

    // ---------------- LATENT (mean/logv/Z fused; ENC from LDS) -------------
    for (int idx=gtid; idx<MLEN*LATD; idx+=NTOT){
        int i=idx/LATD, l=idx%LATD;
        const float* e = &big_lds[(long)i*HD];
        const float* wmr = w_mean + (long)l*HD;
        float am = b_mean[l];
        for (int kk=0;kk<HD;kk+=4){
            f32x4 wv = *(const f32x4*)(wmr+kk);
            f32x4 ev = *(const f32x4*)(e+kk);
            am = fmaf(wv[0],ev[0],am); am = fmaf(wv[1],ev[1],am);
            am = fmaf(wv[2],ev[2],am); am = fmaf(wv[3],ev[3],am);
        }
        const float* wlr = w_logv + (long)l*HD;
        float al = b_logv[l];
        for (int kk=0;kk<HD;kk+=4){
            f32x4 wv = *(const f32x4*)(wlr+kk);
            f32x4 ev = *(const f32x4*)(e+kk);
            al = fmaf(wv[0],ev[0],al); al = fmaf(wv[1],ev[1],al);
            al = fmaf(wv[2],ev[2],al); al = fmaf(wv[3],ev[3],al);
        }
        out_mean[idx] = am;
        out_logv[idx] = al;
        stf(&Zf[idx], eps[idx]*__expf(0.5f*al) + am);
    }
    gridbar(slots, flags, ++ep);   // Z visible
    for (int idx=gtid; idx<MLEN*HD; idx+=NTOT){
        int i=idx/HD, j=idx%HD;
        const float* zr = Zf + (long)i*LATD;
        const float* wr = w_l2h + (long)j*LATD;
        float acc = b_l2h[j];
        for (int kk=0;kk<LATD;kk+=4){
            float4 wv = *(const float4*)(wr+kk);
            float4 zv = *(const float4*)(zr+kk);
            acc = fmaf(wv.x,zv.x,acc); acc = fmaf(wv.y,zv.y,acc);
            acc = fmaf(wv.z,zv.z,acc); acc = fmaf(wv.w,zv.w,acc);
        }
        stf(&LATf[idx], acc);
    }
    gridbar(slots, flags, ++ep);   // LAT visible
    // Mf j-major: Mf[j*MLEN + i] = dot(comb_w[j,600:], LAT[i,:])
    for (int idx=gtid; idx<MLEN*HD; idx+=NTOT){
        int j=idx/MLEN, i=idx%MLEN;
        const float* wr = comb_w + (long)j*1200 + HD;
        const float* lr = LATf + (long)i*HD;
        float acc = 0.f;
        for (int kk=0;kk<HD;kk+=4){
            float4 wv = *(const float4*)(wr+kk);
            float4 lv = *(const float4*)(lr+kk);
            acc = fmaf(wv.x,lv.x,acc); acc = fmaf(wv.y,lv.y,acc);
            acc = fmaf(wv.z,lv.z,acc); acc = fmaf(wv.w,lv.w,acc);
        }
        stf(&Mf[idx], acc);
    }
    gridbar(slots, flags, ++ep);   // M visible

    // ---------------- DECODER (50 steps, data-poll sync) ----------------
    {
        // Mf -> LDS (cached float4 reads)
        for (int idx=tid; idx<HD*MLEN/4; idx+=NTHR)
            *(f32x4*)&big_lds[4*idx] = *(const f32x4*)&Mf[4*idx];

        // attention weight rows -> registers: wave wid owns rows wid, wid+8, ...
        float awr[7][10];
        #pragma unroll
        for (int ai=0; ai<7; ai++){
            int a = wid + 8*ai;
            #pragma unroll
            for (int i=0;i<10;i++){
                int kk = lane + 64*i;
                awr[ai][i] = (a < MLEN && kk < HD) ? attn_w[(long)a*1200 + HD + kk] : 0.f;
            }
        }

        const float* wih = dir ? dec_wih_b : dec_wih_f;
        const float* bih = dir ? dec_bih_b : dec_bih_f;
        const float* whh = dir ? dec_whh_b : dec_whh_f;
        const float* bhh = dir ? dec_bhh_b : dec_bhh_f;
        float ur[10], uz[10], un[10];
        #pragma unroll
        for (int i=0;i<10;i++){
            int k2 = lane + 64*i;
            bool ok = k2 < HD;
            ur[i] = ok ? wih[(long)k*HD + k2] : 0.f;
            uz[i] = ok ? wih[(long)(HHD+k)*HD + k2] : 0.f;
            un[i] = ok ? wih[(long)(2*HHD+k)*HD + k2] : 0.f;
        }
        float vr[5], vz[5], vn[5];
        #pragma unroll
        for (int i=0;i<5;i++){
            int k2 = lane + 64*i;
            bool ok = k2 < HHD;
            vr[i] = ok ? whh[(long)k*HHD + k2] : 0.f;
            vz[i] = ok ? whh[(long)(HHD+k)*HHD + k2] : 0.f;
            vn[i] = ok ? whh[(long)(2*HHD+k)*HHD + k2] : 0.f;
        }
        const float bir = bih[k], biz = bih[HHD+k], bin_ = bih[2*HHD+k];
        const float bhr = bhh[k], bhz = bhh[HHD+k], bhn = bhh[2*HHD+k];

        for (int t=0; t<TTGT; t++){
            if (t){
                if (tid < HD/4)
                    *(f32x4*)&h_lds[4*tid] = poll16(&HSs[(long)(t-1)*ESTR + 4*tid]);
            }
            // t==0: h_lds still holds ENC row 47
            float cp0 = CPREf[(long)t*HD + tid];
            float cp1 = (tid < HD-NTHR) ? CPREf[(long)t*HD + NTHR + tid] : 0.f;
            __syncthreads();
            // attention scores — weights from registers (zero-masked past HD;
            // h_lds pads are zero so unguarded fmaf is exact)
            #pragma unroll
            for (int ai=0; ai<7; ai++){
                int a = wid + 8*ai;
                if (a < MLEN){
                    float acc = 0.f;
                    #pragma unroll
                    for (int i=0;i<10;i++)
                        acc = fmaf(awr[ai][i], h_lds[lane + 64*i], acc);
                    #pragma unroll
                    for (int off=32;off;off>>=1) acc += __shfl_xor(acc,off);
                    if (lane==0) s_lds[a] = acc + APREf[t*MLEN + a];
                }
            }
            __syncthreads();
            // softmax — bit-exact to R1: butterfly fmax (assoc/comm), per-lane exp,
            // ascending serial sum via shuffles, e*inv
            if (wid==0){
                float v = (lane<MLEN) ? s_lds[lane] : -1e30f;
                float m = v;
                #pragma unroll
                for (int off=32;off;off>>=1) m = fmaxf(m, __shfl_xor(m,off));
                float e = (lane<MLEN) ? __expf(v-m) : 0.f;
                float sum = 0.f;
                #pragma unroll
                for (int a=0;a<MLEN;a++) sum += __shfl(e, a);   // ascending order
                float inv = 1.f/sum;
                if (lane<MLEN) aw_lds[lane] = e*inv;
            }
            __syncthreads();
            // o = relu(CPRE + M^T aw) — Mf from LDS, i ascending
            for (int j=tid; j<HD; j+=NTHR){
                float acc = (j==tid) ? cp0 : cp1;
                const float* mr = &big_lds[j*MLEN];
                #pragma unroll
                for (int i=0;i<MLEN;i++) acc = fmaf(mr[i], aw_lds[i], acc);
                o_lds[j] = fmaxf(acc, 0.f);
            }
            __syncthreads();
            // GRU cells
            float ar=0,az=0,an=0, hr=0,hz=0,hn=0;
            #pragma unroll
            for (int i=0;i<10;i++){
                float ov = o_lds[lane + 64*i];
                ar = fmaf(ur[i], ov, ar);
                az = fmaf(uz[i], ov, az);
                an = fmaf(un[i], ov, an);
            }
            #pragma unroll
            for (int i=0;i<5;i++){
                float hv = h_lds[dir*HHD + lane + 64*i];
                hr = fmaf(vr[i], hv, hr);
                hz = fmaf(vz[i], hv, hz);
                hn = fmaf(vn[i], hv, hn);
            }
            redu6(ar,az,an,hr,hz,hn);
            if (lane==0){
                float r = sigf(ar + bir + hr + bhr);
                float zg = sigf(az + biz + hz + bhz);
                float n = tanhf(an + bin_ + r*(hn + bhn));
                float hnew = (1.f-zg)*n + zg*h_lds[gw];
                // direct per-wave store — earliest possible issue
                stf(&HSs[(long)t*ESTR + gw], hnew);
                HSv[(long)t*HD + gw] = hnew;   // plain, for k_vocab
            }
            __syncthreads();   // protect h_lds before next step's poll
        }
    }
}

// ---------------- vocab projection: bf16 MFMA, fused f32->bf16 ----------------
__device__ __forceinline__ s16x8 pack8(const float* __restrict__ p){
    s16x8 r;
    #pragma unroll
    for (int i=0;i<8;i++){
        unsigned u = __float_as_uint(p[i]);
        r[i] = (short)((u + 0x7fffu + ((u>>16)&1u)) >> 16);
    }
    return r;
}

__global__ void __launch_bounds__(256) k_vocab(const float* __restrict__ out_w,
        const float* __restrict__ out_b, const float* __restrict__ HS,
        float* __restrict__ logits){
    int lane = threadIdx.x & 63, wid = threadIdx.x >> 6;
    int vbase = blockIdx.x*64 + wid*16;
    int arow  = vbase + (lane & 15);
    int kg    = (lane >> 4) * 8;
    bool aok  = arow < VSZ;
    const float* ap = out_w + (long)(aok ? arow : 0) * HD;
    int t0 = lane & 15;
    f32x4 acc0 = {0,0,0,0}, acc1 = acc0, acc2 = acc0, acc3 = acc0;
    const s16x8 zf = (s16x8)0;

    for (int ks=0; ks<19; ks++){
        int kb = ks*32 + kg;
        bool kok = kb < HD;
        s16x8 a = (aok && kok) ? pack8(ap + kb) : zf;
        s16x8 b0 = kok              ? pack8(HS + (long)(t0     )*HD + kb) : zf;
        s16x8 b1 = kok              ? pack8(HS + (long)(t0 + 16)*HD + kb) : zf;
        s16x8 b2 = kok              ? pack8(HS + (long)(t0 + 32)*HD + kb) : zf;
        s16x8 b3 = (kok && t0 < 2)  ? pack8(HS + (long)(t0 + 48)*HD + kb) : zf;
        acc0 = __builtin_amdgcn_mfma_f32_16x16x32_bf16(a, b0, acc0, 0,0,0);
        acc1 = __builtin_amdgcn_mfma_f32_16x16x32_bf16(a, b1, acc1, 0,0,0);
        acc2 = __builtin_amdgcn_mfma_f32_16x16x32_bf16(a, b2, acc2, 0,0,0);
        acc3 = __builtin_amdgcn_mfma_f32_16x16x32_bf16(a, b3, acc3, 0,0,0);
    }

    int vst = vbase + (lane>>4)*4;
    float bb[4];
    #pragma unroll
    for (int r=0;r<4;r++) bb[r] = (vst+r < VSZ) ? out_b[vst+r] : 0.f;
    #pragma unroll
    for (int f=0; f<4; f++){
        int t = t0 + 16*f;
        if (t >= TTGT) continue;
        const f32x4 acc = f==0?acc0 : f==1?acc1 : f==2?acc2 : acc3;
        float* rowp = logits + (long)t*VSZ;
        #pragma unroll
        for (int r=0;r<4;r++){
            int v = vst + r;
            if (v < VSZ) rowp[v] = acc[r] + bb[r];
        }
    }
}

// ---------------- log-softmax: 2-pass, 200 blocks each ----------------
#define LCH 12500   // chunk = VSZ/4

__global__ void __launch_bounds__(256) k_lsm1(const float* __restrict__ logits,
                                              float* __restrict__ part){
    __shared__ float red[8];
    int row = blockIdx.x >> 2, c = blockIdx.x & 3;
    const float* x = logits + (long)row*VSZ + c*LCH;
    int tid = threadIdx.x, lane = tid&63, w = tid>>6;
    float m = -1e30f;
    for (int v=tid; v<LCH; v+=256) m = fmaxf(m, x[v]);
    #pragma unroll
    for (int off=32;off;off>>=1) m = fmaxf(m, __shfl_xor(m,off));
    if (lane==0) red[w] = m;
    __syncthreads();
    float mm = fmaxf(fmaxf(red[0],red[1]),fmaxf(red[2],red[3]));
    float s = 0.f;
    for (int v=tid; v<LCH; v+=256) s += __expf(x[v]-mm);
    #pragma unroll
    for (int off=32;off;off>>=1) s += __shfl_xor(s,off);
    if (lane==0) red[4+w] = s;
    __syncthreads();
    if (tid==0){
        part[(row*4+c)*2+0] = mm;
        part[(row*4+c)*2+1] = red[4]+red[5]+red[6]+red[7];
    }
}

__global__ void __launch_bounds__(256) k_lsm2(float* __restrict__ logits,
                                              const float* __restrict__ part){
    int row = blockIdx.x >> 2, c = blockIdx.x & 3;
    const float* pr = part + row*8;
    float M = fmaxf(fmaxf(pr[0],pr[2]),fmaxf(pr[4],pr[6]));
    float S = pr[1]*__expf(pr[0]-M);
    S += pr[3]*__expf(pr[2]-M);
    S += pr[5]*__expf(pr[4]-M);
    S += pr[7]*__expf(pr[6]-M);
    float L = logf(S);
    float* x = logits + (long)row*VSZ + c*LCH;
    for (int v=threadIdx.x; v<LCH; v+=256) x[v] = x[v] - M - L;
}

extern "C" void kernel_launch(void* const* d_in, const int* in_sizes, int n_in,
                              void* d_out, int out_size, void* d_ws, size_t ws_size,
                              hipStream_t stream) {
    const float* emb_enc   = (const float*)d_in[0];
    const float* emb_dec   = (const float*)d_in[1];
    const float* enc_wih_f = (const float*)d_in[2];
    const float* enc_whh_f = (const float*)d_in[3];
    const float* enc_bih_f = (const float*)d_in[4];
    const float* enc_bhh_f = (const float*)d_in[5];
    const float* enc_wih_b = (const float*)d_in[6];
    const float* enc_whh_b = (const float*)d_in[7];
    const float* enc_bih_b = (const float*)d_in[8];
    const float* enc_bhh_b = (const float*)d_in[9];
    const float* dec_wih_f = (const float*)d_in[10];
    const float* dec_whh_f = (const float*)d_in[11];
    const float* dec_bih_f = (const float*)d_in[12];
    const float* dec_bhh_f = (const float*)d_in[13];
    const float* dec_wih_b = (const float*)d_in[14];
    const float* dec_whh_b = (const float*)d_in[15];
    const float* dec_bih_b = (const float*)d_in[16];
    const float* dec_bhh_b = (const float*)d_in[17];
    const float* w_mean    = (const float*)d_in[18];
    const float* b_mean    = (const float*)d_in[19];
    const float* w_logv    = (const float*)d_in[20];
    const float* b_logv    = (const float*)d_in[21];
    const float* w_l2h     = (const float*)d_in[22];
    const float* b_l2h     = (const float*)d_in[23];
    const float* attn_w    = (const float*)d_in[24];
    const float* attn_b    = (const float*)d_in[25];
    const float* comb_w    = (const float*)d_in[26];
    const float* comb_b    = (const float*)d_in[27];
    const float* out_w     = (const float*)d_in[28];
    const float* out_b     = (const float*)d_in[29];
    const float* eps       = (const float*)d_in[30];
    const int*   in_toks   = (const int*)d_in[31];
    const int*   tgt_toks  = (const int*)d_in[32];

    float* ws = (float*)d_ws;                  // all offsets 128B-aligned
    float* GIf   = ws;                         // 48*1800 = 86400
    float* ENCf  = ws + 86400;                 // 50*640  = 32000
    float* Zf    = ws + 118400;                // 5024
    float* LATf  = ws + 123424;                // 30016
    float* Mf    = ws + 153440;                // 30016 ([j][i], stride 50)
    float* APREf = ws + 183456;                // 2528
    float* CPREf = ws + 185984;                // 30016
    float* HSs   = ws + 216000;                // 50*640 = 32000 (padded state)
    float* HSv   = ws + 248000;                // 50*600 = 30016 (for k_vocab)
    int*   slots = (int*)(ws + 278016);        // 75*32 ints
    int*   flags = (int*)(ws + 280416);        // 75*32 ints
    float* PART  = ws + 282816;                // 400 floats (lsm partials)

    float* dec_out  = (float*)d_out;
    float* out_mean = dec_out + 2500000;
    float* out_logv = dec_out + 2505000;

    k_init<<<(2*NBLK*SLOT_STRIDE + 255)/256, 256, 0, stream>>>((int*)(ws + 278016));

    k_seq<<<NBLK, NTHR, 0, stream>>>(
        emb_enc, emb_dec,
        enc_wih_f, enc_whh_f, enc_bih_f, enc_bhh_f,
        enc_wih_b, enc_whh_b, enc_bih_b, enc_bhh_b,
        dec_wih_f, dec_whh_f, dec_bih_f, dec_bhh_f,
        dec_wih_b, dec_whh_b, dec_bih_b, dec_bhh_b,
        w_mean, b_mean, w_logv, b_logv, w_l2h, b_l2h,
        attn_w, attn_b, comb_w, comb_b,
        eps, in_toks, tgt_toks,
        GIf, ENCf, Zf, LATf, Mf, APREf, CPREf, HSs, HSv,
        out_mean, out_logv, slots, flags);

    k_vocab<<<(VSZ + 63)/64, 256, 0, stream>>>(out_w, out_b, HSv, dec_out);
    k_lsm1<<<200, 256, 0, stream>>>(dec_out, PART);
    k_lsm2<<<200, 256, 0, stream>>>(dec_out, PART);
}

// Round 12
// 779.820 us; speedup vs baseline: 1.0877x; 1.0877x over previous
//
#include <hip/hip_runtime.h>
#include <math.h>

#define VSZ 50000
#define HD 600
#define HHD 300
#define LATD 100
#define MLEN 50
#define TIN 48
#define TTGT 50
#define NBLK 75
#define NTHR 512
#define NTOT (NBLK*NTHR)
#define ESTR 640              // padded row stride
#define SLOT_STRIDE 32        // ints; 128B between slots
#define SENTU 0x40000000u     // 2.0f — impossible GRU output (|h| < 1 strictly)

typedef __attribute__((ext_vector_type(4))) float f32x4;
typedef __attribute__((ext_vector_type(8))) short s16x8;

__device__ __forceinline__ float sigf(float x){ return 1.0f/(1.0f+__expf(-x)); }

// agent-scope store (write-through to coherent point)
__device__ __forceinline__ void stf(float* p, float v){
    __hip_atomic_store((unsigned int*)p, __float_as_uint(v),
                       __ATOMIC_RELAXED, __HIP_MEMORY_SCOPE_AGENT);
}
__device__ __forceinline__ void stu(float* p, unsigned v){
    __hip_atomic_store((unsigned int*)p, v,
                       __ATOMIC_RELAXED, __HIP_MEMORY_SCOPE_AGENT);
}
__device__ __forceinline__ int ldslot(const int* p){
    return __hip_atomic_load(p, __ATOMIC_RELAXED, __HIP_MEMORY_SCOPE_AGENT);
}
__device__ __forceinline__ void stslot(int* p, int v){
    __hip_atomic_store(p, v, __ATOMIC_RELAXED, __HIP_MEMORY_SCOPE_AGENT);
}

// uncached 16B load (bypasses L1+L2 -> coherent point), waits completion
__device__ __forceinline__ f32x4 ld_unc16(const float* p){
    f32x4 r;
    asm volatile("global_load_dwordx4 %0, %1, off sc0 sc1\n\ts_waitcnt vmcnt(0)"
                 : "=v"(r) : "v"(p) : "memory");
    return r;
}
// poll a 16B chunk until no word equals the sentinel
__device__ __forceinline__ f32x4 poll16(const float* p){
    f32x4 r = ld_unc16(p);
    while (__float_as_uint(r[0])==SENTU || __float_as_uint(r[1])==SENTU ||
           __float_as_uint(r[2])==SENTU || __float_as_uint(r[3])==SENTU){
        __builtin_amdgcn_s_sleep(1);
        r = ld_unc16(p);
    }
    return r;
}

__device__ __forceinline__ void redu3(float&a,float&b,float&c){
    #pragma unroll
    for(int off=32;off;off>>=1){
        a+=__shfl_xor(a,off); b+=__shfl_xor(b,off); c+=__shfl_xor(c,off);
    }
}
__device__ __forceinline__ void redu6(float&a,float&b,float&c,float&d,float&e,float&f){
    #pragma unroll
    for(int off=32;off;off>>=1){
        a+=__shfl_xor(a,off); b+=__shfl_xor(b,off); c+=__shfl_xor(c,off);
        d+=__shfl_xor(d,off); e+=__shfl_xor(e,off); f+=__shfl_xor(f,off);
    }
}

// Two-level leader barrier (4 uses: pre + latent x3)
__device__ __forceinline__ void gridbar(int* slots, int* flags, int e){
    asm volatile("s_waitcnt vmcnt(0)" ::: "memory");
    __syncthreads();
    const int tid = threadIdx.x;
    if (tid == 0) stslot(&slots[blockIdx.x*SLOT_STRIDE], e);
    if (blockIdx.x == 0){
        if (tid < NBLK){
            while (ldslot(&slots[tid*SLOT_STRIDE]) < e)
                __builtin_amdgcn_s_sleep(1);
        }
        __syncthreads();
        if (tid < NBLK) stslot(&flags[tid*SLOT_STRIDE], e);
    } else {
        if (tid == 0){
            while (ldslot(&flags[blockIdx.x*SLOT_STRIDE]) < e)
                __builtin_amdgcn_s_sleep(1);
        }
    }
    __syncthreads();
}

__global__ void k_init(int* sync_mem){
    int i = blockIdx.x*blockDim.x + threadIdx.x;
    if (i < 2*NBLK*SLOT_STRIDE) sync_mem[i] = 0;
}

__global__ void __launch_bounds__(NTHR, 2) k_seq(
    const float* __restrict__ emb_enc, const float* __restrict__ emb_dec,
    const float* __restrict__ enc_wih_f, const float* __restrict__ enc_whh_f,
    const float* __restrict__ enc_bih_f, const float* __restrict__ enc_bhh_f,
    const float* __restrict__ enc_wih_b, const float* __restrict__ enc_whh_b,
    const float* __restrict__ enc_bih_b, const float* __restrict__ enc_bhh_b,
    const float* __restrict__ dec_wih_f, const float* __restrict__ dec_whh_f,
    const float* __restrict__ dec_bih_f, const float* __restrict__ dec_bhh_f,
    const float* __restrict__ dec_wih_b, const float* __restrict__ dec_whh_b,
    const float* __restrict__ dec_bih_b, const float* __restrict__ dec_bhh_b,
    const float* __restrict__ w_mean, const float* __restrict__ b_mean,
    const float* __restrict__ w_logv, const float* __restrict__ b_logv,
    const float* __restrict__ w_l2h, const float* __restrict__ b_l2h,
    const float* __restrict__ attn_w, const float* __restrict__ attn_b,
    const float* __restrict__ comb_w, const float* __restrict__ comb_b,
    const float* __restrict__ eps, const int* __restrict__ in_toks,
    const int* __restrict__ tgt_toks,
    float* __restrict__ GIf, float* __restrict__ ENCf,
    float* __restrict__ Zf, float* __restrict__ LATf, float* __restrict__ Mf,
    float* __restrict__ APREf, float* __restrict__ CPREf,
    float* __restrict__ HSs, float* __restrict__ HSv,
    float* __restrict__ out_mean, float* __restrict__ out_logv,
    int* slots, int* flags){

    __shared__ float h_lds[ESTR];
    __shared__ float o_lds[ESTR];
    __shared__ float s_lds[64];
    __shared__ float aw_lds[64];
    __shared__ float hv_lds[8];
    __shared__ float big_lds[HD*MLEN];  // encoder: ENC[50][600]; decoder: Mf[600][50]

    const int tid  = threadIdx.x;
    const int lane = tid & 63;
    const int wid  = tid >> 6;
    const int gtid = blockIdx.x*NTHR + tid;
    const int gw   = blockIdx.x*8 + wid;      // 0..599, == dir*HHD + k
    const int dir  = gw / HHD;
    const int k    = gw % HHD;
    int ep = 0;

    // own-direction chunk range for encoder polling (mixed block 37 -> full row)
    const int dlo = (blockIdx.x*8) / HHD, dhi = (blockIdx.x*8 + 7) / HHD;
    const int clo = (dlo==dhi) ? dlo*75 : 0;
    const int chi = (dlo==dhi) ? clo+75 : 150;
    const int flo = 4*clo, fhi = 4*chi;

    // zero ALL of h_lds/o_lds (incl. other-direction half + pads) — masked-weight
    // FMAs read these as finite zeros
    for (int j=tid; j<ESTR; j+=NTHR){ h_lds[j]=0.f; o_lds[j]=0.f; }

    // ---------------- PRE PHASE ----------------
    for (int idx=gtid; idx<TIN*HD; idx+=NTOT){
        int t=idx/HD, j=idx%HD;
        stu(&ENCf[(long)t*ESTR + j], SENTU);
    }
    for (int idx=gtid; idx<TTGT*HD; idx+=NTOT){
        int t=idx/HD, j=idx%HD;
        stu(&HSs[(long)t*ESTR + j], SENTU);
    }
    // GI: R1-exact bias-seeded single fmaf chain
    for (int idx=gtid; idx<TIN*1800; idx+=NTOT){
        int t=idx/1800, r=idx%1800, d=r/900, j=r%900;
        const float* w  = d ? enc_wih_b : enc_wih_f;
        const float* bi = d ? enc_bih_b : enc_bih_f;
        const float* x  = emb_enc + (long)in_toks[t]*HD;
        const float* wr = w + (long)j*HD;
        float acc = bi[j];
        for (int kk=0;kk<HD;kk+=4){
            float4 wv = *(const float4*)(wr+kk);
            float4 xv = *(const float4*)(x+kk);
            acc = fmaf(wv.x,xv.x,acc); acc = fmaf(wv.y,xv.y,acc);
            acc = fmaf(wv.z,xv.z,acc); acc = fmaf(wv.w,xv.w,acc);
        }
        stf(&GIf[idx], acc);
    }
    for (int idx=gtid; idx<TTGT*MLEN; idx+=NTOT){
        int t=idx/MLEN, a=idx%MLEN;
        int tok = t ? tgt_toks[t-1] : 1;
        const float* x  = emb_dec + (long)tok*HD;
        const float* wr = attn_w + (long)a*1200;
        float acc = attn_b[a];
        for (int kk=0;kk<HD;kk+=4){
            float4 wv = *(const float4*)(wr+kk);
            float4 xv = *(const float4*)(x+kk);
            acc = fmaf(wv.x,xv.x,acc); acc = fmaf(wv.y,xv.y,acc);
            acc = fmaf(wv.z,xv.z,acc); acc = fmaf(wv.w,xv.w,acc);
        }
        stf(&APREf[idx], acc);
    }
    for (int idx=gtid; idx<TTGT*HD; idx+=NTOT){
        int t=idx/HD, j=idx%HD;
        int tok = t ? tgt_toks[t-1] : 1;
        const float* x  = emb_dec + (long)tok*HD;
        const float* wr = comb_w + (long)j*1200;
        float acc = comb_b[j];
        for (int kk=0;kk<HD;kk+=4){
            float4 wv = *(const float4*)(wr+kk);
            float4 xv = *(const float4*)(x+kk);
            acc = fmaf(wv.x,xv.x,acc); acc = fmaf(wv.y,xv.y,acc);
            acc = fmaf(wv.z,xv.z,acc); acc = fmaf(wv.w,xv.w,acc);
        }
        stf(&CPREf[idx], acc);
    }
    gridbar(slots, flags, ++ep);   // sentinels + GI/APRE/CPRE visible

    // ---------------- ENCODER (48 steps, per-direction data-poll) ----------
    {
        const float* whh = dir ? enc_whh_b : enc_whh_f;
        const float* bhh = dir ? enc_bhh_b : enc_bhh_f;
        float wr_[5], wz_[5], wn_[5];
        #pragma unroll
        for (int i=0;i<5;i++){
            int k2 = lane + 64*i;
            bool ok = k2 < HHD;
            wr_[i] = ok ? whh[(long)k*HHD + k2] : 0.f;
            wz_[i] = ok ? whh[(long)(HHD+k)*HHD + k2] : 0.f;
            wn_[i] = ok ? whh[(long)(2*HHD+k)*HHD + k2] : 0.f;
        }
        const float bhr = bhh[k], bhz = bhh[HHD+k], bhn = bhh[2*HHD+k];
        float gr=0, gz=0, gn=0;
        if (lane < TIN){
            const float* g = GIf + (long)lane*1800 + dir*900;   // cached, post-bar
            gr = g[k]; gz = g[HHD+k]; gn = g[2*HHD+k];
        }
        for (int t=0; t<TIN; t++){
            if (t){
                if (tid < chi-clo)
                    *(f32x4*)&h_lds[4*(clo+tid)] = poll16(&ENCf[(long)(t-1)*ESTR + 4*(clo+tid)]);
            }
            // t==0: h_lds already fully zero
            __syncthreads();
            if (t){   // archive own half of row t-1
                for (int j=flo+tid; j<fhi; j+=NTHR)
                    big_lds[(long)(t-1)*HD + j] = h_lds[j];
            }
            float sr=0, sz=0, sn=0;
            #pragma unroll
            for (int i=0;i<5;i++){
                float hv = h_lds[dir*HHD + lane + 64*i];
                sr = fmaf(wr_[i], hv, sr);
                sz = fmaf(wz_[i], hv, sz);
                sn = fmaf(wn_[i], hv, sn);
            }
            redu3(sr, sz, sn);
            float grt=__shfl(gr,t), gzt=__shfl(gz,t), gnt=__shfl(gn,t);
            if (lane==0){
                float r = sigf(grt + sr + bhr);
                float z = sigf(gzt + sz + bhz);
                float n = tanhf(gnt + r*(sn + bhn));
                float hp = h_lds[gw];
                hv_lds[wid] = (1.f-z)*n + z*hp;
            }
            __syncthreads();
            // batched coalesced store: one wave, 8 consecutive words
            if (tid < 8) stf(&ENCf[(long)t*ESTR + blockIdx.x*8 + tid], hv_lds[tid]);
        }
        // epilogue: pull row 47 FULL (gates on both chains), archive, zeros 48/49
        if (tid < HD/4)
            *(f32x4*)&h_lds[4*tid] = poll16(&ENCf[(long)(TIN-1)*ESTR + 4*tid]);
        __syncthreads();
        big_lds[(long)(TIN-1)*HD + tid] = h_lds[tid];
        if (tid < HD-NTHR) big_lds[(long)(TIN-1)*HD + NTHR + tid] = h_lds[NTHR+tid];
        big_lds[(long)TIN*HD + tid] = 0.f;
        big_lds[(long)TIN*HD + NTHR + tid] = 0.f;
        if (tid < 2*HD - 2*NTHR) big_lds[(long)TIN*HD + 2*NTHR + tid] = 0.f;
        // bulk-fill other-direction halves of rows 0..46
        {
            int compn = 150 - (chi - clo);
            for (int q=tid; q<47*compn; q+=NTHR){
                int row = q / compn, c = q % compn;
                int ch = (c < clo) ? c : (c + (chi - clo));
                *(f32x4*)&big_lds[(long)row*HD + 4*ch] =
                    poll16(&ENCf[(long)row*ESTR + 4*ch]);
            }
        }
        __syncthreads();
    }

    // ---------------- LATENT (mean/logv/Z fused; ENC from LDS) -------------
    for (int idx=gtid; idx<MLEN*LATD; idx+=NTOT){
        int i=idx/LATD, l=idx%LATD;
        const float* e = &big_lds[(long)i*HD];
        const float* wmr = w_mean + (long)l*HD;
        float am = b_mean[l];
        for (int kk=0;kk<HD;kk+=4){
            f32x4 wv = *(const f32x4*)(wmr+kk);
            f32x4 ev = *(const f32x4*)(e+kk);
            am = fmaf(wv[0],ev[0],am); am = fmaf(wv[1],ev[1],am);
            am = fmaf(wv[2],ev[2],am); am = fmaf(wv[3],ev[3],am);
        }
        const float* wlr = w_logv + (long)l*HD;
        float al = b_logv[l];
        for (int kk=0;kk<HD;kk+=4){
            f32x4 wv = *(const f32x4*)(wlr+kk);
            f32x4 ev = *(const f32x4*)(e+kk);
            al = fmaf(wv[0],ev[0],al); al = fmaf(wv[1],ev[1],al);
            al = fmaf(wv[2],ev[2],al); al = fmaf(wv[3],ev[3],al);
        }
        out_mean[idx] = am;
        out_logv[idx] = al;
        stf(&Zf[idx], eps[idx]*__expf(0.5f*al) + am);
    }
    gridbar(slots, flags, ++ep);   // Z visible
    for (int idx=gtid; idx<MLEN*HD; idx+=NTOT){
        int i=idx/HD, j=idx%HD;
        const float* zr = Zf + (long)i*LATD;
        const float* wr = w_l2h + (long)j*LATD;
        float acc = b_l2h[j];
        for (int kk=0;kk<LATD;kk+=4){
            float4 wv = *(const float4*)(wr+kk);
            float4 zv = *(const float4*)(zr+kk);
            acc = fmaf(wv.x,zv.x,acc); acc = fmaf(wv.y,zv.y,acc);
            acc = fmaf(wv.z,zv.z,acc); acc = fmaf(wv.w,zv.w,acc);
        }
        stf(&LATf[idx], acc);
    }
    gridbar(slots, flags, ++ep);   // LAT visible
    // Mf j-major: Mf[j*MLEN + i] = dot(comb_w[j,600:], LAT[i,:])
    for (int idx=gtid; idx<MLEN*HD; idx+=NTOT){
        int j=idx/MLEN, i=idx%MLEN;
        const float* wr = comb_w + (long)j*1200 + HD;
        const float* lr = LATf + (long)i*HD;
        float acc = 0.f;
        for (int kk=0;kk<HD;kk+=4){
            float4 wv = *(const float4*)(wr+kk);
            float4 lv = *(const float4*)(lr+kk);
            acc = fmaf(wv.x,lv.x,acc); acc = fmaf(wv.y,lv.y,acc);
            acc = fmaf(wv.z,lv.z,acc); acc = fmaf(wv.w,lv.w,acc);
        }
        stf(&Mf[idx], acc);
    }
    gridbar(slots, flags, ++ep);   // M visible

    // ---------------- DECODER (50 steps, data-poll sync) ----------------
    {
        // Mf -> LDS (cached float4 reads)
        for (int idx=tid; idx<HD*MLEN/4; idx+=NTHR)
            *(f32x4*)&big_lds[4*idx] = *(const f32x4*)&Mf[4*idx];

        // attention weight rows -> registers: wave wid owns rows wid, wid+8, ...
        float awr[7][10];
        #pragma unroll
        for (int ai=0; ai<7; ai++){
            int a = wid + 8*ai;
            #pragma unroll
            for (int i=0;i<10;i++){
                int kk = lane + 64*i;
                awr[ai][i] = (a < MLEN && kk < HD) ? attn_w[(long)a*1200 + HD + kk] : 0.f;
            }
        }

        const float* wih = dir ? dec_wih_b : dec_wih_f;
        const float* bih = dir ? dec_bih_b : dec_bih_f;
        const float* whh = dir ? dec_whh_b : dec_whh_f;
        const float* bhh = dir ? dec_bhh_b : dec_bhh_f;
        float ur[10], uz[10], un[10];
        #pragma unroll
        for (int i=0;i<10;i++){
            int k2 = lane + 64*i;
            bool ok = k2 < HD;
            ur[i] = ok ? wih[(long)k*HD + k2] : 0.f;
            uz[i] = ok ? wih[(long)(HHD+k)*HD + k2] : 0.f;
            un[i] = ok ? wih[(long)(2*HHD+k)*HD + k2] : 0.f;
        }
        float vr[5], vz[5], vn[5];
        #pragma unroll
        for (int i=0;i<5;i++){
            int k2 = lane + 64*i;
            bool ok = k2 < HHD;
            vr[i] = ok ? whh[(long)k*HHD + k2] : 0.f;
            vz[i] = ok ? whh[(long)(HHD+k)*HHD + k2] : 0.f;
            vn[i] = ok ? whh[(long)(2*HHD+k)*HHD + k2] : 0.f;
        }
        const float bir = bih[k], biz = bih[HHD+k], bin_ = bih[2*HHD+k];
        const float bhr = bhh[k], bhz = bhh[HHD+k], bhn = bhh[2*HHD+k];

        for (int t=0; t<TTGT; t++){
            if (t){
                if (tid < HD/4)
                    *(f32x4*)&h_lds[4*tid] = poll16(&HSs[(long)(t-1)*ESTR + 4*tid]);
            }
            // t==0: h_lds still holds ENC row 47
            float cp0 = CPREf[(long)t*HD + tid];
            float cp1 = (tid < HD-NTHR) ? CPREf[(long)t*HD + NTHR + tid] : 0.f;
            __syncthreads();
            // attention scores — weights from registers (zero-masked past HD;
            // h_lds pads are zero so unguarded fmaf is exact)
            #pragma unroll
            for (int ai=0; ai<7; ai++){
                int a = wid + 8*ai;
                if (a < MLEN){
                    float acc = 0.f;
                    #pragma unroll
                    for (int i=0;i<10;i++)
                        acc = fmaf(awr[ai][i], h_lds[lane + 64*i], acc);
                    #pragma unroll
                    for (int off=32;off;off>>=1) acc += __shfl_xor(acc,off);
                    if (lane==0) s_lds[a] = acc + APREf[t*MLEN + a];
                }
            }
            __syncthreads();
            // softmax — bit-exact to R1: butterfly fmax (assoc/comm), per-lane exp,
            // ascending serial sum via shuffles, e*inv
            if (wid==0){
                float v = (lane<MLEN) ? s_lds[lane] : -1e30f;
                float m = v;
                #pragma unroll
                for (int off=32;off;off>>=1) m = fmaxf(m, __shfl_xor(m,off));
                float e = (lane<MLEN) ? __expf(v-m) : 0.f;
                float sum = 0.f;
                #pragma unroll
                for (int a=0;a<MLEN;a++) sum += __shfl(e, a);   // ascending order
                float inv = 1.f/sum;
                if (lane<MLEN) aw_lds[lane] = e*inv;
            }
            __syncthreads();
            // o = relu(CPRE + M^T aw) — Mf from LDS, i ascending
            for (int j=tid; j<HD; j+=NTHR){
                float acc = (j==tid) ? cp0 : cp1;
                const float* mr = &big_lds[j*MLEN];
                #pragma unroll
                for (int i=0;i<MLEN;i++) acc = fmaf(mr[i], aw_lds[i], acc);
                o_lds[j] = fmaxf(acc, 0.f);
            }
            __syncthreads();
            // GRU cells
            float ar=0,az=0,an=0, hr=0,hz=0,hn=0;
            #pragma unroll
            for (int i=0;i<10;i++){
                float ov = o_lds[lane + 64*i];
                ar = fmaf(ur[i], ov, ar);
                az = fmaf(uz[i], ov, az);
                an = fmaf(un[i], ov, an);
            }
            #pragma unroll
            for (int i=0;i<5;i++){
                float hv = h_lds[dir*HHD + lane + 64*i];
                hr = fmaf(vr[i], hv, hr);
                hz = fmaf(vz[i], hv, hz);
                hn = fmaf(vn[i], hv, hn);
            }
            redu6(ar,az,an,hr,hz,hn);
            if (lane==0){
                float r = sigf(ar + bir + hr + bhr);
                float zg = sigf(az + biz + hz + bhz);
                float n = tanhf(an + bin_ + r*(hn + bhn));
                hv_lds[wid] = (1.f-zg)*n + zg*h_lds[gw];
            }
            __syncthreads();
            // batched coalesced stores: one wave, 8 consecutive words
            if (tid < 8){
                float hnew = hv_lds[tid];
                stf(&HSs[(long)t*ESTR + blockIdx.x*8 + tid], hnew);
                HSv[(long)t*HD + blockIdx.x*8 + tid] = hnew;   // plain, for k_vocab
            }
        }
    }
}

// ---------------- vocab projection: bf16 MFMA, fused f32->bf16 ----------------
__device__ __forceinline__ s16x8 pack8(const float* __restrict__ p){
    s16x8 r;
    #pragma unroll
    for (int i=0;i<8;i++){
        unsigned u = __float_as_uint(p[i]);
        r[i] = (short)((u + 0x7fffu + ((u>>16)&1u)) >> 16);
    }
    return r;
}

__global__ void __launch_bounds__(256) k_vocab(const float* __restrict__ out_w,
        const float* __restrict__ out_b, const float* __restrict__ HS,
        float* __restrict__ logits){
    int lane = threadIdx.x & 63, wid = threadIdx.x >> 6;
    int vbase = blockIdx.x*64 + wid*16;
    int arow  = vbase + (lane & 15);
    int kg    = (lane >> 4) * 8;
    bool aok  = arow < VSZ;
    const float* ap = out_w + (long)(aok ? arow : 0) * HD;
    int t0 = lane & 15;
    f32x4 acc0 = {0,0,0,0}, acc1 = acc0, acc2 = acc0, acc3 = acc0;
    const s16x8 zf = (s16x8)0;

    for (int ks=0; ks<19; ks++){
        int kb = ks*32 + kg;
        bool kok = kb < HD;
        s16x8 a = (aok && kok) ? pack8(ap + kb) : zf;
        s16x8 b0 = kok              ? pack8(HS + (long)(t0     )*HD + kb) : zf;
        s16x8 b1 = kok              ? pack8(HS + (long)(t0 + 16)*HD + kb) : zf;
        s16x8 b2 = kok              ? pack8(HS + (long)(t0 + 32)*HD + kb) : zf;
        s16x8 b3 = (kok && t0 < 2)  ? pack8(HS + (long)(t0 + 48)*HD + kb) : zf;
        acc0 = __builtin_amdgcn_mfma_f32_16x16x32_bf16(a, b0, acc0, 0,0,0);
        acc1 = __builtin_amdgcn_mfma_f32_16x16x32_bf16(a, b1, acc1, 0,0,0);
        acc2 = __builtin_amdgcn_mfma_f32_16x16x32_bf16(a, b2, acc2, 0,0,0);
        acc3 = __builtin_amdgcn_mfma_f32_16x16x32_bf16(a, b3, acc3, 0,0,0);
    }

    int vst = vbase + (lane>>4)*4;
    float bb[4];
    #pragma unroll
    for (int r=0;r<4;r++) bb[r] = (vst+r < VSZ) ? out_b[vst+r] : 0.f;
    #pragma unroll
    for (int f=0; f<4; f++){
        int t = t0 + 16*f;
        if (t >= TTGT) continue;
        const f32x4 acc = f==0?acc0 : f==1?acc1 : f==2?acc2 : acc3;
        float* rowp = logits + (long)t*VSZ;
        #pragma unroll
        for (int r=0;r<4;r++){
            int v = vst + r;
            if (v < VSZ) rowp[v] = acc[r] + bb[r];
        }
    }
}

// ---------------- log-softmax: 2-pass, 200 blocks each ----------------
#define LCH 12500   // chunk = VSZ/4

__global__ void __launch_bounds__(256) k_lsm1(const float* __restrict__ logits,
                                              float* __restrict__ part){
    __shared__ float red[8];
    int row = blockIdx.x >> 2, c = blockIdx.x & 3;
    const float* x = logits + (long)row*VSZ + c*LCH;
    int tid = threadIdx.x, lane = tid&63, w = tid>>6;
    float m = -1e30f;
    for (int v=tid; v<LCH; v+=256) m = fmaxf(m, x[v]);
    #pragma unroll
    for (int off=32;off;off>>=1) m = fmaxf(m, __shfl_xor(m,off));
    if (lane==0) red[w] = m;
    __syncthreads();
    float mm = fmaxf(fmaxf(red[0],red[1]),fmaxf(red[2],red[3]));
    float s = 0.f;
    for (int v=tid; v<LCH; v+=256) s += __expf(x[v]-mm);
    #pragma unroll
    for (int off=32;off;off>>=1) s += __shfl_xor(s,off);
    if (lane==0) red[4+w] = s;
    __syncthreads();
    if (tid==0){
        part[(row*4+c)*2+0] = mm;
        part[(row*4+c)*2+1] = red[4]+red[5]+red[6]+red[7];
    }
}

__global__ void __launch_bounds__(256) k_lsm2(float* __restrict__ logits,
                                              const float* __restrict__ part){
    int row = blockIdx.x >> 2, c = blockIdx.x & 3;
    const float* pr = part + row*8;
    float M = fmaxf(fmaxf(pr[0],pr[2]),fmaxf(pr[4],pr[6]));
    float S = pr[1]*__expf(pr[0]-M);
    S += pr[3]*__expf(pr[2]-M);
    S += pr[5]*__expf(pr[4]-M);
    S += pr[7]*__expf(pr[6]-M);
    float L = logf(S);
    float* x = logits + (long)row*VSZ + c*LCH;
    for (int v=threadIdx.x; v<LCH; v+=256) x[v] = x[v] - M - L;
}

extern "C" void kernel_launch(void* const* d_in, const int* in_sizes, int n_in,
                              void* d_out, int out_size, void* d_ws, size_t ws_size,
                              hipStream_t stream) {
    const float* emb_enc   = (const float*)d_in[0];
    const float* emb_dec   = (const float*)d_in[1];
    const float* enc_wih_f = (const float*)d_in[2];
    const float* enc_whh_f = (const float*)d_in[3];
    const float* enc_bih_f = (const float*)d_in[4];
    const float* enc_bhh_f = (const float*)d_in[5];
    const float* enc_wih_b = (const float*)d_in[6];
    const float* enc_whh_b = (const float*)d_in[7];
    const float* enc_bih_b = (const float*)d_in[8];
    const float* enc_bhh_b = (const float*)d_in[9];
    const float* dec_wih_f = (const float*)d_in[10];
    const float* dec_whh_f = (const float*)d_in[11];
    const float* dec_bih_f = (const float*)d_in[12];
    const float* dec_bhh_f = (const float*)d_in[13];
    const float* dec_wih_b = (const float*)d_in[14];
    const float* dec_whh_b = (const float*)d_in[15];
    const float* dec_bih_b = (const float*)d_in[16];
    const float* dec_bhh_b = (const float*)d_in[17];
    const float* w_mean    = (const float*)d_in[18];
    const float* b_mean    = (const float*)d_in[19];
    const float* w_logv    = (const float*)d_in[20];
    const float* b_logv    = (const float*)d_in[21];
    const float* w_l2h     = (const float*)d_in[22];
    const float* b_l2h     = (const float*)d_in[23];
    const float* attn_w    = (const float*)d_in[24];
    const float* attn_b    = (const float*)d_in[25];
    const float* comb_w    = (const float*)d_in[26];
    const float* comb_b    = (const float*)d_in[27];
    const float* out_w     = (const float*)d_in[28];
    const float* out_b     = (const float*)d_in[29];
    const float* eps       = (const float*)d_in[30];
    const int*   in_toks   = (const int*)d_in[31];
    const int*   tgt_toks  = (const int*)d_in[32];

    float* ws = (float*)d_ws;                  // all offsets 128B-aligned
    float* GIf   = ws;                         // 48*1800 = 86400
    float* ENCf  = ws + 86400;                 // 50*640  = 32000
    float* Zf    = ws + 118400;                // 5024
    float* LATf  = ws + 123424;                // 30016
    float* Mf    = ws + 153440;                // 30016 ([j][i], stride 50)
    float* APREf = ws + 183456;                // 2528
    float* CPREf = ws + 185984;                // 30016
    float* HSs   = ws + 216000;                // 50*640 = 32000 (padded state)
    float* HSv   = ws + 248000;                // 50*600 = 30016 (for k_vocab)
    int*   slots = (int*)(ws + 278016);        // 75*32 ints
    int*   flags = (int*)(ws + 280416);        // 75*32 ints
    float* PART  = ws + 282816;                // 400 floats (lsm partials)

    float* dec_out  = (float*)d_out;
    float* out_mean = dec_out + 2500000;
    float* out_logv = dec_out + 2505000;

    k_init<<<(2*NBLK*SLOT_STRIDE + 255)/256, 256, 0, stream>>>((int*)(ws + 278016));

    k_seq<<<NBLK, NTHR, 0, stream>>>(
        emb_enc, emb_dec,
        enc_wih_f, enc_whh_f, enc_bih_f, enc_bhh_f,
        enc_wih_b, enc_whh_b, enc_bih_b, enc_bhh_b,
        dec_wih_f, dec_whh_f, dec_bih_f, dec_bhh_f,
        dec_wih_b, dec_whh_b, dec_bih_b, dec_bhh_b,
        w_mean, b_mean, w_logv, b_logv, w_l2h, b_l2h,
        attn_w, attn_b, comb_w, comb_b,
        eps, in_toks, tgt_toks,
        GIf, ENCf, Zf, LATf, Mf, APREf, CPREf, HSs, HSv,
        out_mean, out_logv, slots, flags);

    k_vocab<<<(VSZ + 63)/64, 256, 0, stream>>>(out_w, out_b, HSv, dec_out);
    k_lsm1<<<200, 256, 0, stream>>>(dec_out, PART);
    k_lsm2<<<200, 256, 0, stream>>>(dec_out, PART);
}